// Round 1
// baseline (1081.754 us; speedup 1.0000x reference)
//
#include <hip/hip_runtime.h>
#include <math.h>

#define SEQ 2048
#define NB 2
#define NTOK (NB * SEQ)      // 4096
#define DIM 1024
#define NHEADS 8
#define DHEAD 128
#define FQKV 3072            // 3 * DIM_INNER
#define DIM_INNER 1024
#define SC_ATTN 0.08838834764831843f   // 128^-0.5
#define SC_NORM 32.0f                  // sqrt(1024)

// ---------------------------------------------------------------------------
// Kernel 1: L2 norm over last dim, scale by sqrt(DIM) * gamma
// one block per token, 256 threads, 1 float4 per thread
// ---------------------------------------------------------------------------
__global__ __launch_bounds__(256) void l2norm_kernel(const float* __restrict__ x,
                                                     const float* __restrict__ gamma,
                                                     float* __restrict__ xn) {
    int token = blockIdx.x;
    const float4* xp = (const float4*)(x + (size_t)token * DIM);
    float4 v = xp[threadIdx.x];
    float ss = v.x * v.x + v.y * v.y + v.z * v.z + v.w * v.w;
#pragma unroll
    for (int off = 32; off > 0; off >>= 1) ss += __shfl_down(ss, off);
    __shared__ float wsum[4];
    if ((threadIdx.x & 63) == 0) wsum[threadIdx.x >> 6] = ss;
    __syncthreads();
    float tot = wsum[0] + wsum[1] + wsum[2] + wsum[3];
    float scale = SC_NORM / fmaxf(sqrtf(tot), 1e-12f);
    const float4* gp = (const float4*)gamma;
    float4 g = gp[threadIdx.x];
    float4 o;
    o.x = v.x * scale * g.x;
    o.y = v.y * scale * g.y;
    o.z = v.z * scale * g.z;
    o.w = v.w * scale * g.w;
    ((float4*)(xn + (size_t)token * DIM))[threadIdx.x] = o;
}

// ---------------------------------------------------------------------------
// Kernel 2/4: C[M][N] = A[M][K] * B[N][K]^T   (both row-major, K contiguous)
// 128x128 tile, 256 threads, 8x8 micro-tile (split 4+4), TK=16
// LDS stride 132 floats: 16B-aligned rows, <=2-way bank conflicts (free)
// ---------------------------------------------------------------------------
__global__ __launch_bounds__(256) void gemm_nt(const float* __restrict__ A,
                                               const float* __restrict__ B,
                                               float* __restrict__ C,
                                               int M, int N, int K) {
    const int TK = 16;
    const int LDT = 132;   // 128 + 4 pad
    __shared__ float As[TK * LDT];
    __shared__ float Bs[TK * LDT];
    int bm = blockIdx.y * 128;
    int bn = blockIdx.x * 128;
    int tid = threadIdx.x;
    int tr = tid >> 4;     // 0..15
    int tc = tid & 15;     // 0..15

    float acc[8][8] = {};

    for (int k0 = 0; k0 < K; k0 += TK) {
        // stage A,B tiles: 128 rows x 16 k = 512 float4 each, 2 per thread
#pragma unroll
        for (int it = 0; it < 2; ++it) {
            int idx = tid + it * 256;
            int m = idx >> 2;
            int kv = idx & 3;
            float4 a4 = *(const float4*)(A + (size_t)(bm + m) * K + k0 + kv * 4);
            As[(kv * 4 + 0) * LDT + m] = a4.x;
            As[(kv * 4 + 1) * LDT + m] = a4.y;
            As[(kv * 4 + 2) * LDT + m] = a4.z;
            As[(kv * 4 + 3) * LDT + m] = a4.w;
            float4 b4 = *(const float4*)(B + (size_t)(bn + m) * K + k0 + kv * 4);
            Bs[(kv * 4 + 0) * LDT + m] = b4.x;
            Bs[(kv * 4 + 1) * LDT + m] = b4.y;
            Bs[(kv * 4 + 2) * LDT + m] = b4.z;
            Bs[(kv * 4 + 3) * LDT + m] = b4.w;
        }
        __syncthreads();
#pragma unroll
        for (int kk = 0; kk < TK; ++kk) {
            float a[8], b[8];
            float4 t0 = *(const float4*)(As + kk * LDT + tr * 4);
            float4 t1 = *(const float4*)(As + kk * LDT + 64 + tr * 4);
            a[0] = t0.x; a[1] = t0.y; a[2] = t0.z; a[3] = t0.w;
            a[4] = t1.x; a[5] = t1.y; a[6] = t1.z; a[7] = t1.w;
            float4 u0 = *(const float4*)(Bs + kk * LDT + tc * 4);
            float4 u1 = *(const float4*)(Bs + kk * LDT + 64 + tc * 4);
            b[0] = u0.x; b[1] = u0.y; b[2] = u0.z; b[3] = u0.w;
            b[4] = u1.x; b[5] = u1.y; b[6] = u1.z; b[7] = u1.w;
#pragma unroll
            for (int i = 0; i < 8; ++i)
#pragma unroll
                for (int j = 0; j < 8; ++j)
                    acc[i][j] += a[i] * b[j];
        }
        __syncthreads();
    }

    // write C: rows {bm+tr*4+i, bm+64+tr*4+i}, cols {bn+tc*4+j, bn+64+tc*4+j}
#pragma unroll
    for (int ih = 0; ih < 2; ++ih)
#pragma unroll
        for (int i = 0; i < 4; ++i) {
            int row = bm + ih * 64 + tr * 4 + i;
            float4 o0, o1;
            o0.x = acc[ih * 4 + i][0]; o0.y = acc[ih * 4 + i][1];
            o0.z = acc[ih * 4 + i][2]; o0.w = acc[ih * 4 + i][3];
            o1.x = acc[ih * 4 + i][4]; o1.y = acc[ih * 4 + i][5];
            o1.z = acc[ih * 4 + i][6]; o1.w = acc[ih * 4 + i][7];
            *(float4*)(C + (size_t)row * N + bn + tc * 4) = o0;
            *(float4*)(C + (size_t)row * N + bn + 64 + tc * 4) = o1;
        }
}

// ---------------------------------------------------------------------------
// Kernel 3: causal flash attention, fp32
// grid (SEQ/QB, H, B), 256 threads. QB=32 q-rows, KB=64 kv-cols per tile.
// K and V time-share one LDS buffer. XOR-swizzled LDS (conflict-free b128).
// Thread t: rp=t>>4 (2 q-rows 2rp,2rp+1), cg=t&15 (4 S-cols / 8 O-d-floats).
// ---------------------------------------------------------------------------
#define QB 32
#define KB 64

__global__ __launch_bounds__(256) void attn_kernel(const float* __restrict__ qkv,
                                                   float* __restrict__ out) {
    __shared__ float Qs[QB * 128];    // swizzled
    __shared__ float KVs[KB * 128];   // swizzled; K then V
    __shared__ float Ps[QB * 66];

    int qblk = gridDim.x - 1 - blockIdx.x;   // long blocks first
    int h = blockIdx.y;
    int b = blockIdx.z;
    int tid = threadIdx.x;
    int q0 = qblk * QB;

    // ---- load Q tile (scaled), swizzled store ----
#pragma unroll
    for (int it = 0; it < 4; ++it) {
        int idx = tid + it * 256;
        int r = idx >> 5;         // 0..31
        int vec = idx & 31;       // float4 index within row
        const float* src = qkv + ((size_t)(b * SEQ + q0 + r)) * FQKV + h * DHEAD + vec * 4;
        float4 v = *(const float4*)src;
        v.x *= SC_ATTN; v.y *= SC_ATTN; v.z *= SC_ATTN; v.w *= SC_ATTN;
        *(float4*)(Qs + r * 128 + ((vec ^ (r & 7)) << 2)) = v;
    }

    int rp = tid >> 4;            // 0..15
    int cg = tid & 15;            // 0..15
    int r0 = 2 * rp, r1 = 2 * rp + 1;
    int i0 = q0 + r0, i1 = q0 + r1;

    float m[2] = {-1e38f, -1e38f};
    float l[2] = {0.f, 0.f};
    float O[2][2][4];
#pragma unroll
    for (int e = 0; e < 2; ++e)
#pragma unroll
        for (int ii = 0; ii < 2; ++ii)
#pragma unroll
            for (int j = 0; j < 4; ++j) O[e][ii][j] = 0.f;

    int ntiles = (q0 + QB - 1) / KB + 1;
    for (int jb = 0; jb < ntiles; ++jb) {
        __syncthreads();   // prev PV done with KVs/Ps (and Q visible, iter 0)

        // ---- load K tile (64 x 128), swizzled ----
#pragma unroll
        for (int it = 0; it < 8; ++it) {
            int idx = tid + it * 256;
            int rr = idx >> 5;
            int vec = idx & 31;
            const float* src = qkv + ((size_t)(b * SEQ + jb * KB + rr)) * FQKV
                               + DIM_INNER + h * DHEAD + vec * 4;
            float4 v = *(const float4*)src;
            *(float4*)(KVs + rr * 128 + ((vec ^ (rr & 7)) << 2)) = v;
        }
        __syncthreads();

        // ---- S = Q K^T for this tile: thread owns rows r0,r1 x cols cg+16*cc ----
        float sa[2][4] = {{0.f, 0.f, 0.f, 0.f}, {0.f, 0.f, 0.f, 0.f}};
#pragma unroll 4
        for (int d = 0; d < 128; d += 4) {
            int ch = d >> 2;
            float4 qv0 = *(const float4*)(Qs + r0 * 128 + ((ch ^ (r0 & 7)) << 2));
            float4 qv1 = *(const float4*)(Qs + r1 * 128 + ((ch ^ (r1 & 7)) << 2));
#pragma unroll
            for (int cc = 0; cc < 4; ++cc) {
                int c = cg + 16 * cc;
                float4 kv = *(const float4*)(KVs + c * 128 + ((ch ^ (c & 7)) << 2));
                sa[0][cc] += qv0.x * kv.x + qv0.y * kv.y + qv0.z * kv.z + qv0.w * kv.w;
                sa[1][cc] += qv1.x * kv.x + qv1.y * kv.y + qv1.z * kv.z + qv1.w * kv.w;
            }
        }

        // ---- online softmax update (per row, 16-lane butterfly) ----
        float alph[2];
#pragma unroll
        for (int e = 0; e < 2; ++e) {
            int ig = e ? i1 : i0;
            float tmax = -1e38f;
#pragma unroll
            for (int cc = 0; cc < 4; ++cc) {
                int j = jb * KB + cg + 16 * cc;
                if (j > ig) sa[e][cc] = -1e38f;
                tmax = fmaxf(tmax, sa[e][cc]);
            }
#pragma unroll
            for (int off = 1; off < 16; off <<= 1)
                tmax = fmaxf(tmax, __shfl_xor(tmax, off));
            float Mn = fmaxf(m[e], tmax);
            float psum = 0.f;
#pragma unroll
            for (int cc = 0; cc < 4; ++cc) {
                int j = jb * KB + cg + 16 * cc;
                float p = (j <= ig) ? __expf(sa[e][cc] - Mn) : 0.f;
                psum += p;
                Ps[(2 * rp + e) * 66 + cg + 16 * cc] = p;
            }
#pragma unroll
            for (int off = 1; off < 16; off <<= 1)
                psum += __shfl_xor(psum, off);
            float alpha = __expf(m[e] - Mn);
            l[e] = l[e] * alpha + psum;
            m[e] = Mn;
            alph[e] = alpha;
        }
        __syncthreads();   // K reads done, P visible

        // ---- load V tile into same buffer ----
#pragma unroll
        for (int it = 0; it < 8; ++it) {
            int idx = tid + it * 256;
            int rr = idx >> 5;
            int vec = idx & 31;
            const float* src = qkv + ((size_t)(b * SEQ + jb * KB + rr)) * FQKV
                               + 2 * DIM_INNER + h * DHEAD + vec * 4;
            float4 v = *(const float4*)src;
            *(float4*)(KVs + rr * 128 + ((vec ^ (rr & 7)) << 2)) = v;
        }
        __syncthreads();

        // ---- O = O*alpha + P V : thread owns rows r0,r1 x d = cg*4+ii*64..+3 ----
#pragma unroll
        for (int e = 0; e < 2; ++e)
#pragma unroll
            for (int ii = 0; ii < 2; ++ii)
#pragma unroll
                for (int j = 0; j < 4; ++j) O[e][ii][j] *= alph[e];

        int kmax = q0 + QB - jb * KB;
        if (kmax > KB) kmax = KB;
        for (int k = 0; k < kmax; ++k) {
            float p0 = Ps[r0 * 66 + k];
            float p1 = Ps[r1 * 66 + k];
#pragma unroll
            for (int ii = 0; ii < 2; ++ii) {
                int ch = cg + 16 * ii;
                float4 v = *(const float4*)(KVs + k * 128 + ((ch ^ (k & 7)) << 2));
                O[0][ii][0] += p0 * v.x; O[0][ii][1] += p0 * v.y;
                O[0][ii][2] += p0 * v.z; O[0][ii][3] += p0 * v.w;
                O[1][ii][0] += p1 * v.x; O[1][ii][1] += p1 * v.y;
                O[1][ii][2] += p1 * v.z; O[1][ii][3] += p1 * v.w;
            }
        }
    }

    // ---- epilogue: O / l -> out[b][i][h*128+d] ----
    float inv[2] = {1.0f / l[0], 1.0f / l[1]};
#pragma unroll
    for (int e = 0; e < 2; ++e) {
        int ig = e ? i1 : i0;
        float* dst = out + ((size_t)(b * SEQ + ig)) * DIM_INNER + h * DHEAD;
#pragma unroll
        for (int ii = 0; ii < 2; ++ii) {
            float4 o;
            o.x = O[e][ii][0] * inv[e];
            o.y = O[e][ii][1] * inv[e];
            o.z = O[e][ii][2] * inv[e];
            o.w = O[e][ii][3] * inv[e];
            *(float4*)(dst + (cg + 16 * ii) * 4) = o;
        }
    }
}

// ---------------------------------------------------------------------------
extern "C" void kernel_launch(void* const* d_in, const int* in_sizes, int n_in,
                              void* d_out, int out_size, void* d_ws, size_t ws_size,
                              hipStream_t stream) {
    const float* x     = (const float*)d_in[0];
    const float* gamma = (const float*)d_in[1];
    const float* w_qkv = (const float*)d_in[2];
    const float* w_out = (const float*)d_in[3];
    float* out = (float*)d_out;

    float* xn  = (float*)d_ws;                    // 4096*1024 floats; reused as attn-out
    float* qkv = xn + (size_t)NTOK * DIM;         // 4096*3072 floats

    l2norm_kernel<<<NTOK, 256, 0, stream>>>(x, gamma, xn);

    gemm_nt<<<dim3(FQKV / 128, NTOK / 128), 256, 0, stream>>>(
        xn, w_qkv, qkv, NTOK, FQKV, DIM);

    attn_kernel<<<dim3(SEQ / QB, NHEADS, NB), 256, 0, stream>>>(qkv, xn);

    gemm_nt<<<dim3(DIM / 128, NTOK / 128), 256, 0, stream>>>(
        xn, w_out, out, NTOK, DIM, DIM);
}

// Round 2
// 147.376 us; speedup vs baseline: 7.3401x; 7.3401x over previous
//
#include <hip/hip_runtime.h>

#define SEQ 2048
#define NTOK 4096
#define DIM 1024
#define FQKV 3072
#define SC_ATTN 0.08838834764831843f   // 128^-0.5
#define SC_NORM 32.0f                  // sqrt(1024)

typedef short short8 __attribute__((ext_vector_type(8)));
typedef float f32x4 __attribute__((ext_vector_type(4)));
typedef unsigned short u16x4 __attribute__((ext_vector_type(4)));

__device__ __forceinline__ unsigned short f2bf(float f) {
    unsigned int u = __float_as_uint(f);
    u += 0x7fffu + ((u >> 16) & 1u);   // RNE
    return (unsigned short)(u >> 16);
}
__device__ __forceinline__ float bf2f(unsigned short b) {
    return __uint_as_float(((unsigned int)b) << 16);
}
__device__ __forceinline__ void gl_lds16(const void* g, void* l) {
    __builtin_amdgcn_global_load_lds((const __attribute__((address_space(1))) void*)g,
                                     (__attribute__((address_space(3))) void*)l, 16, 0, 0);
}

// ---------------------------------------------------------------------------
// L2 norm -> bf16
// ---------------------------------------------------------------------------
__global__ __launch_bounds__(256) void l2norm_bf16(const float* __restrict__ x,
                                                   const float* __restrict__ gamma,
                                                   unsigned short* __restrict__ xn) {
    int token = blockIdx.x;
    float4 v = ((const float4*)(x + (size_t)token * DIM))[threadIdx.x];
    float ss = v.x * v.x + v.y * v.y + v.z * v.z + v.w * v.w;
#pragma unroll
    for (int off = 32; off > 0; off >>= 1) ss += __shfl_down(ss, off);
    __shared__ float wsum[4];
    if ((threadIdx.x & 63) == 0) wsum[threadIdx.x >> 6] = ss;
    __syncthreads();
    float tot = wsum[0] + wsum[1] + wsum[2] + wsum[3];
    float sc = SC_NORM / fmaxf(sqrtf(tot), 1e-12f);
    float4 g = ((const float4*)gamma)[threadIdx.x];
    u16x4 o;
    o.x = f2bf(v.x * sc * g.x);
    o.y = f2bf(v.y * sc * g.y);
    o.z = f2bf(v.z * sc * g.z);
    o.w = f2bf(v.w * sc * g.w);
    ((u16x4*)(xn + (size_t)token * DIM))[threadIdx.x] = o;
}

// ---------------------------------------------------------------------------
// fp32 -> bf16 weight convert
// ---------------------------------------------------------------------------
__global__ __launch_bounds__(256) void wconv(const float* __restrict__ w,
                                             unsigned short* __restrict__ o, int n4) {
    int i = blockIdx.x * 256 + threadIdx.x;
    if (i >= n4) return;
    float4 v = ((const float4*)w)[i];
    u16x4 r;
    r.x = f2bf(v.x); r.y = f2bf(v.y); r.z = f2bf(v.z); r.w = f2bf(v.w);
    ((u16x4*)o)[i] = r;
}

// ---------------------------------------------------------------------------
// bf16 GEMM NT: C[M][N] = A[M][K] * B[N][K]^T. 128x128 tile, BK=64, 4 waves.
// global_load_lds(16B) with pre-swizzled source; XOR-(row&7) chunk swizzle so
// ds_read_b128 fragment reads are conflict-free per 16-lane phase.
// C_MODE 0: f32 out. C_MODE 1: bf16 out, cols<1024 scaled by SC_ATTN (Q).
// ---------------------------------------------------------------------------
template<int C_MODE>
__global__ __launch_bounds__(256) void gemm_bf16(const unsigned short* __restrict__ A,
                                                 const unsigned short* __restrict__ B,
                                                 void* __restrict__ Cv,
                                                 int M, int N, int K) {
    __shared__ unsigned short As[128 * 64];
    __shared__ unsigned short Bs[128 * 64];
    const int bn = blockIdx.x * 128, bm = blockIdx.y * 128;
    const int tid = threadIdx.x, lane = tid & 63, wv = tid >> 6;
    const int wr = wv >> 1, wc = wv & 1;
    const int l15 = lane & 15, g = lane >> 4;

    f32x4 acc[4][4] = {};

    for (int k0 = 0; k0 < K; k0 += 64) {
        __syncthreads();
#pragma unroll
        for (int inst = 0; inst < 4; ++inst) {
            int ci = inst * 256 + wv * 64 + lane;
            int row = ci >> 3, cc = ci & 7;
            int co = (cc ^ (row & 7)) << 3;
            gl_lds16(A + (size_t)(bm + row) * K + k0 + co, &As[(inst * 256 + wv * 64) * 8]);
            gl_lds16(B + (size_t)(bn + row) * K + k0 + co, &Bs[(inst * 256 + wv * 64) * 8]);
        }
        __syncthreads();
#pragma unroll
        for (int ks = 0; ks < 2; ++ks) {
            short8 af[4], bf[4];
#pragma unroll
            for (int f = 0; f < 4; ++f) {
                int ra = wr * 64 + f * 16 + l15;
                af[f] = *(const short8*)&As[ra * 64 + (((ks * 4 + g) ^ (ra & 7)) << 3)];
                int rb = wc * 64 + f * 16 + l15;
                bf[f] = *(const short8*)&Bs[rb * 64 + (((ks * 4 + g) ^ (rb & 7)) << 3)];
            }
#pragma unroll
            for (int i = 0; i < 4; ++i)
#pragma unroll
                for (int j = 0; j < 4; ++j)
                    acc[i][j] = __builtin_amdgcn_mfma_f32_16x16x32_bf16(af[i], bf[j], acc[i][j], 0, 0, 0);
        }
    }

    if (C_MODE == 0) {
        float* C = (float*)Cv;
#pragma unroll
        for (int i = 0; i < 4; ++i)
#pragma unroll
            for (int j = 0; j < 4; ++j)
#pragma unroll
                for (int v = 0; v < 4; ++v) {
                    int row = bm + wr * 64 + i * 16 + g * 4 + v;
                    int col = bn + wc * 64 + j * 16 + l15;
                    C[(size_t)row * N + col] = acc[i][j][v];
                }
    } else {
        unsigned short* C = (unsigned short*)Cv;
        float s = (bn < 1024) ? SC_ATTN : 1.0f;
#pragma unroll
        for (int i = 0; i < 4; ++i)
#pragma unroll
            for (int j = 0; j < 4; ++j)
#pragma unroll
                for (int v = 0; v < 4; ++v) {
                    int row = bm + wr * 64 + i * 16 + g * 4 + v;
                    int col = bn + wc * 64 + j * 16 + l15;
                    C[(size_t)row * N + col] = f2bf(acc[i][j][v] * s);
                }
    }
}

// ---------------------------------------------------------------------------
// V transpose: qkv V-part [token][d] -> vt[(b*8+h)*128 + d][token]
// ---------------------------------------------------------------------------
__global__ __launch_bounds__(256) void transpose_v(const unsigned short* __restrict__ qkv,
                                                   unsigned short* __restrict__ vt) {
    __shared__ unsigned short T[64][72];
    const int t0 = blockIdx.x * 64, d0 = blockIdx.y * 64, bh = blockIdx.z;
    const int b = bh >> 3, h = bh & 7;
    const int tid = threadIdx.x;
#pragma unroll
    for (int p = 0; p < 2; ++p) {
        int r = p * 32 + (tid >> 3), c = tid & 7;
        *(short8*)&T[r][c * 8] =
            *(const short8*)(qkv + (size_t)(b * SEQ + t0 + r) * FQKV + 2048 + h * 128 + d0 + c * 8);
    }
    __syncthreads();
#pragma unroll
    for (int p = 0; p < 2; ++p) {
        int d = p * 32 + (tid >> 3), c = tid & 7;
        short8 v;
#pragma unroll
        for (int j = 0; j < 8; ++j) v[j] = (short)T[c * 8 + j][d];
        *(short8*)(vt + (size_t)(bh * 128 + d0 + d) * SEQ + t0 + c * 8) = v;
    }
}

// ---------------------------------------------------------------------------
// Flash attention, bf16 MFMA. 4 waves x 16 q-rows (QB=64), KB=64.
// Swapped QK^T: S^T = mfma(K, Q) -> lane holds 16 kv for q-row (lane&15);
// softmax reduce = shfl_xor(16),(32). P -> swizzled per-wave LDS -> A-frag.
// PV: B-frag from pre-transposed V tile (Vt[d][kv]).
// ---------------------------------------------------------------------------
__global__ __launch_bounds__(256) void attn_mfma(const unsigned short* __restrict__ qkv,
                                                 const unsigned short* __restrict__ vt,
                                                 unsigned short* __restrict__ ao) {
    __shared__ unsigned short Ks[64 * 128];
    __shared__ unsigned short Vs[128 * 64];
    __shared__ unsigned short Ps[4][16 * 64];
    const int qblk = gridDim.x - 1 - blockIdx.x;   // longest blocks first
    const int h = blockIdx.y, b = blockIdx.z;
    const int tid = threadIdx.x, lane = tid & 63, wv = tid >> 6;
    const int l15 = lane & 15, g = lane >> 4;
    const int q0 = qblk * 64;
    const int qrow = q0 + wv * 16 + l15;

    // Q fragments (B-operand): lane: q = l15, d = ks*32 + g*8 + j
    short8 qf[4];
    {
        const unsigned short* qb = qkv + (size_t)(b * SEQ + qrow) * FQKV + h * 128;
#pragma unroll
        for (int ks = 0; ks < 4; ++ks) qf[ks] = *(const short8*)(qb + ks * 32 + g * 8);
    }

    float m_r = -1e30f, l_r = 0.f;
    f32x4 o[8] = {};

    for (int jb = 0; jb <= qblk; ++jb) {
        __syncthreads();
        // stage K tile [64][128] and Vt tile [128][64], pre-swizzled source
#pragma unroll
        for (int inst = 0; inst < 4; ++inst) {
            int ci = inst * 256 + wv * 64 + lane;
            int rowk = ci >> 4, ck = ci & 15;
            gl_lds16(qkv + (size_t)(b * SEQ + jb * 64 + rowk) * FQKV + 1024 + h * 128
                         + ((ck ^ (rowk & 7)) << 3),
                     &Ks[(inst * 256 + wv * 64) * 8]);
            int rowv = ci >> 3, cv = ci & 7;
            gl_lds16(vt + (size_t)((b * 8 + h) * 128 + rowv) * SEQ + jb * 64
                        + ((cv ^ (rowv & 7)) << 3),
                     &Vs[(inst * 256 + wv * 64) * 8]);
        }
        __syncthreads();

        // S^T = K * Q^T : 4 kv-fragments, accumulate over 4 d-slices
        f32x4 s[4] = {};
#pragma unroll
        for (int ks = 0; ks < 4; ++ks) {
#pragma unroll
            for (int fi = 0; fi < 4; ++fi) {
                int rk = fi * 16 + l15;
                short8 kf = *(const short8*)&Ks[rk * 128 + (((ks * 4 + g) ^ (rk & 7)) << 3)];
                s[fi] = __builtin_amdgcn_mfma_f32_16x16x32_bf16(kf, qf[ks], s[fi], 0, 0, 0);
            }
        }

        if (jb == qblk) {   // diagonal tile: causal mask
#pragma unroll
            for (int fi = 0; fi < 4; ++fi)
#pragma unroll
                for (int v = 0; v < 4; ++v) {
                    int kv = q0 + fi * 16 + g * 4 + v;
                    if (kv > qrow) s[fi][v] = -1e30f;
                }
        }

        // online softmax (per q-row = lane&15, group reduce over lanes ^16,^32)
        float mx = -1e30f;
#pragma unroll
        for (int fi = 0; fi < 4; ++fi)
            mx = fmaxf(mx, fmaxf(fmaxf(s[fi][0], s[fi][1]), fmaxf(s[fi][2], s[fi][3])));
        mx = fmaxf(mx, __shfl_xor(mx, 16));
        mx = fmaxf(mx, __shfl_xor(mx, 32));
        float Mn = fmaxf(m_r, mx);
        float alpha = __expf(m_r - Mn);
        m_r = Mn;

        float ps = 0.f;
#pragma unroll
        for (int fi = 0; fi < 4; ++fi) {
#pragma unroll
            for (int p2 = 0; p2 < 2; ++p2) {
                unsigned short b0 = f2bf(__expf(s[fi][2 * p2] - Mn));
                unsigned short b1 = f2bf(__expf(s[fi][2 * p2 + 1] - Mn));
                ps += bf2f(b0) + bf2f(b1);   // denominator from rounded P: consistent with PV
                int kv = fi * 16 + g * 4 + 2 * p2;
                int addr = l15 * 64 + (((kv >> 3) ^ (l15 & 7)) << 3) + (kv & 7);
                *(unsigned int*)&Ps[wv][addr] = (unsigned int)b0 | ((unsigned int)b1 << 16);
            }
        }
        ps += __shfl_xor(ps, 16);
        ps += __shfl_xor(ps, 32);
        l_r = l_r * alpha + ps;

        // rescale O (alpha for row g*4+v lives in lane g*4+v)
        float av[4];
#pragma unroll
        for (int v = 0; v < 4; ++v) av[v] = __shfl(alpha, g * 4 + v);
#pragma unroll
        for (int fn = 0; fn < 8; ++fn) {
            o[fn][0] *= av[0]; o[fn][1] *= av[1]; o[fn][2] *= av[2]; o[fn][3] *= av[3];
        }

        // O += P * V
#pragma unroll
        for (int ks = 0; ks < 2; ++ks) {
            short8 pa = *(const short8*)&Ps[wv][l15 * 64 + (((ks * 4 + g) ^ (l15 & 7)) << 3)];
#pragma unroll
            for (int fn = 0; fn < 8; ++fn) {
                int rv = fn * 16 + l15;
                short8 vf = *(const short8*)&Vs[rv * 64 + (((ks * 4 + g) ^ (rv & 7)) << 3)];
                o[fn] = __builtin_amdgcn_mfma_f32_16x16x32_bf16(pa, vf, o[fn], 0, 0, 0);
            }
        }
    }

    // epilogue: divide by l (row g*4+v's sum lives in lane g*4+v), store bf16
    float lv[4];
#pragma unroll
    for (int v = 0; v < 4; ++v) lv[v] = 1.0f / __shfl(l_r, g * 4 + v);
#pragma unroll
    for (int fn = 0; fn < 8; ++fn)
#pragma unroll
        for (int v = 0; v < 4; ++v) {
            int row = b * SEQ + q0 + wv * 16 + g * 4 + v;
            ao[(size_t)row * DIM + h * 128 + fn * 16 + l15] = f2bf(o[fn][v] * lv[v]);
        }
}

// ---------------------------------------------------------------------------
extern "C" void kernel_launch(void* const* d_in, const int* in_sizes, int n_in,
                              void* d_out, int out_size, void* d_ws, size_t ws_size,
                              hipStream_t stream) {
    const float* x     = (const float*)d_in[0];
    const float* gamma = (const float*)d_in[1];
    const float* w_qkv = (const float*)d_in[2];
    const float* w_out = (const float*)d_in[3];

    char* ws = (char*)d_ws;
    unsigned short* qkvb = (unsigned short*)ws;                   // 25165824 B  [4096][3072]
    unsigned short* vtb  = (unsigned short*)(ws + 25165824);      //  8388608 B  [16][128][2048]
    unsigned short* xnb  = (unsigned short*)(ws + 33554432);      //  8388608 B  [4096][1024]
    unsigned short* wqb  = (unsigned short*)(ws + 41943040);      //  6291456 B  [3072][1024]
    unsigned short* wob  = (unsigned short*)(ws + 48234496);      //  2097152 B  [1024][1024]
    unsigned short* aob  = (unsigned short*)(ws + 50331648);      //  8388608 B  [4096][1024]

    wconv<<<3072, 256, 0, stream>>>(w_qkv, wqb, 786432);
    wconv<<<1024, 256, 0, stream>>>(w_out, wob, 262144);
    l2norm_bf16<<<4096, 256, 0, stream>>>(x, gamma, xnb);
    gemm_bf16<1><<<dim3(24, 32), 256, 0, stream>>>(xnb, wqb, qkvb, NTOK, FQKV, DIM);
    transpose_v<<<dim3(32, 2, 16), 256, 0, stream>>>(qkvb, vtb);
    attn_mfma<<<dim3(32, 8, 2), 256, 0, stream>>>(qkvb, vtb, aob);
    gemm_bf16<0><<<dim3(8, 32), 256, 0, stream>>>(aob, wob, (float*)d_out, NTOK, DIM, DIM);
}

// Round 3
// 143.117 us; speedup vs baseline: 7.5585x; 1.0298x over previous
//
#include <hip/hip_runtime.h>

#define SEQ 2048
#define NTOK 4096
#define DIM 1024
#define FQKV 3072
#define SC_ATTN 0.08838834764831843f   // 128^-0.5
#define SC_NORM 32.0f                  // sqrt(1024)

typedef short short8 __attribute__((ext_vector_type(8)));
typedef float f32x4 __attribute__((ext_vector_type(4)));
typedef unsigned short u16x4 __attribute__((ext_vector_type(4)));

__device__ __forceinline__ unsigned short f2bf(float f) {
    unsigned int u = __float_as_uint(f);
    u += 0x7fffu + ((u >> 16) & 1u);   // RNE
    return (unsigned short)(u >> 16);
}
__device__ __forceinline__ float bf2f(unsigned short b) {
    return __uint_as_float(((unsigned int)b) << 16);
}
__device__ __forceinline__ void gl_lds16(const void* g, void* l) {
    __builtin_amdgcn_global_load_lds((const __attribute__((address_space(1))) void*)g,
                                     (__attribute__((address_space(3))) void*)l, 16, 0, 0);
}

// ---------------------------------------------------------------------------
// L2 norm -> bf16
// ---------------------------------------------------------------------------
__global__ __launch_bounds__(256) void l2norm_bf16(const float* __restrict__ x,
                                                   const float* __restrict__ gamma,
                                                   unsigned short* __restrict__ xn) {
    int token = blockIdx.x;
    float4 v = ((const float4*)(x + (size_t)token * DIM))[threadIdx.x];
    float ss = v.x * v.x + v.y * v.y + v.z * v.z + v.w * v.w;
#pragma unroll
    for (int off = 32; off > 0; off >>= 1) ss += __shfl_down(ss, off);
    __shared__ float wsum[4];
    if ((threadIdx.x & 63) == 0) wsum[threadIdx.x >> 6] = ss;
    __syncthreads();
    float tot = wsum[0] + wsum[1] + wsum[2] + wsum[3];
    float sc = SC_NORM / fmaxf(sqrtf(tot), 1e-12f);
    float4 g = ((const float4*)gamma)[threadIdx.x];
    u16x4 o;
    o.x = f2bf(v.x * sc * g.x);
    o.y = f2bf(v.y * sc * g.y);
    o.z = f2bf(v.z * sc * g.z);
    o.w = f2bf(v.w * sc * g.w);
    ((u16x4*)(xn + (size_t)token * DIM))[threadIdx.x] = o;
}

// ---------------------------------------------------------------------------
// fp32 -> bf16 weight convert
// ---------------------------------------------------------------------------
__global__ __launch_bounds__(256) void wconv(const float* __restrict__ w,
                                             unsigned short* __restrict__ o, int n4) {
    int i = blockIdx.x * 256 + threadIdx.x;
    if (i >= n4) return;
    float4 v = ((const float4*)w)[i];
    u16x4 r;
    r.x = f2bf(v.x); r.y = f2bf(v.y); r.z = f2bf(v.z); r.w = f2bf(v.w);
    ((u16x4*)o)[i] = r;
}

// ---------------------------------------------------------------------------
// bf16 GEMM NT: C[M][N] = A[M][K] * B[N][K]^T. 128x128 tile, BK=64, 4 waves.
// T3 minimum-2-phase: double-buffered LDS, prefetch next K-tile before
// computing current, single __syncthreads per iter (vmcnt(0) drain lands
// after compute). XOR-(row&7) chunk swizzle, conflict-free ds_read_b128.
// ---------------------------------------------------------------------------
template<int C_MODE>
__global__ __launch_bounds__(256) void gemm_bf16(const unsigned short* __restrict__ A,
                                                 const unsigned short* __restrict__ B,
                                                 void* __restrict__ Cv,
                                                 int M, int N, int K) {
    __shared__ unsigned short As[2][128 * 64];
    __shared__ unsigned short Bs[2][128 * 64];
    const int bn = blockIdx.x * 128, bm = blockIdx.y * 128;
    const int tid = threadIdx.x, lane = tid & 63, wv = tid >> 6;
    const int wr = wv >> 1, wc = wv & 1;
    const int l15 = lane & 15, g = lane >> 4;

    f32x4 acc[4][4] = {};

    auto stage = [&](int buf, int k0) {
#pragma unroll
        for (int inst = 0; inst < 4; ++inst) {
            int ci = inst * 256 + wv * 64 + lane;
            int row = ci >> 3, cc = ci & 7;
            int co = (cc ^ (row & 7)) << 3;
            gl_lds16(A + (size_t)(bm + row) * K + k0 + co, &As[buf][(inst * 256 + wv * 64) * 8]);
            gl_lds16(B + (size_t)(bn + row) * K + k0 + co, &Bs[buf][(inst * 256 + wv * 64) * 8]);
        }
    };

    stage(0, 0);
    __syncthreads();
    int cur = 0;
    for (int k0 = 0; k0 < K; k0 += 64) {
        if (k0 + 64 < K) stage(cur ^ 1, k0 + 64);
#pragma unroll
        for (int ks = 0; ks < 2; ++ks) {
            short8 af[4], bf[4];
#pragma unroll
            for (int f = 0; f < 4; ++f) {
                int ra = wr * 64 + f * 16 + l15;
                af[f] = *(const short8*)&As[cur][ra * 64 + (((ks * 4 + g) ^ (ra & 7)) << 3)];
                int rb = wc * 64 + f * 16 + l15;
                bf[f] = *(const short8*)&Bs[cur][rb * 64 + (((ks * 4 + g) ^ (rb & 7)) << 3)];
            }
#pragma unroll
            for (int i = 0; i < 4; ++i)
#pragma unroll
                for (int j = 0; j < 4; ++j)
                    acc[i][j] = __builtin_amdgcn_mfma_f32_16x16x32_bf16(af[i], bf[j], acc[i][j], 0, 0, 0);
        }
        __syncthreads();
        cur ^= 1;
    }

    if (C_MODE == 0) {
        float* C = (float*)Cv;
#pragma unroll
        for (int i = 0; i < 4; ++i)
#pragma unroll
            for (int j = 0; j < 4; ++j)
#pragma unroll
                for (int v = 0; v < 4; ++v) {
                    int row = bm + wr * 64 + i * 16 + g * 4 + v;
                    int col = bn + wc * 64 + j * 16 + l15;
                    C[(size_t)row * N + col] = acc[i][j][v];
                }
    } else {
        unsigned short* C = (unsigned short*)Cv;
        float s = (bn < 1024) ? SC_ATTN : 1.0f;
#pragma unroll
        for (int i = 0; i < 4; ++i)
#pragma unroll
            for (int j = 0; j < 4; ++j)
#pragma unroll
                for (int v = 0; v < 4; ++v) {
                    int row = bm + wr * 64 + i * 16 + g * 4 + v;
                    int col = bn + wc * 64 + j * 16 + l15;
                    C[(size_t)row * N + col] = f2bf(acc[i][j][v] * s);
                }
    }
}

// ---------------------------------------------------------------------------
// V transpose: qkv V-part [token][d] -> vt[(b*8+h)*128 + d][token]
// ---------------------------------------------------------------------------
__global__ __launch_bounds__(256) void transpose_v(const unsigned short* __restrict__ qkv,
                                                   unsigned short* __restrict__ vt) {
    __shared__ unsigned short T[64][72];
    const int t0 = blockIdx.x * 64, d0 = blockIdx.y * 64, bh = blockIdx.z;
    const int b = bh >> 3, h = bh & 7;
    const int tid = threadIdx.x;
#pragma unroll
    for (int p = 0; p < 2; ++p) {
        int r = p * 32 + (tid >> 3), c = tid & 7;
        *(short8*)&T[r][c * 8] =
            *(const short8*)(qkv + (size_t)(b * SEQ + t0 + r) * FQKV + 2048 + h * 128 + d0 + c * 8);
    }
    __syncthreads();
#pragma unroll
    for (int p = 0; p < 2; ++p) {
        int d = p * 32 + (tid >> 3), c = tid & 7;
        short8 v;
#pragma unroll
        for (int j = 0; j < 8; ++j) v[j] = (short)T[c * 8 + j][d];
        *(short8*)(vt + (size_t)(bh * 128 + d0 + d) * SEQ + t0 + c * 8) = v;
    }
}

// ---------------------------------------------------------------------------
// Flash attention, bf16 MFMA. 4 waves x 16 q-rows (QB=64), KB=64.
// Double-buffered K/V with prefetch (T3 minimum-2-phase), single barrier/iter.
// Swapped QK^T, online softmax via shfl_xor, P via per-wave swizzled LDS,
// PV from pre-transposed V. s_setprio around MFMA clusters (T5).
// ---------------------------------------------------------------------------
__global__ __launch_bounds__(256) void attn_mfma(const unsigned short* __restrict__ qkv,
                                                 const unsigned short* __restrict__ vt,
                                                 unsigned short* __restrict__ ao) {
    __shared__ unsigned short Ks[2][64 * 128];
    __shared__ unsigned short Vs[2][128 * 64];
    __shared__ unsigned short Ps[4][16 * 64];
    const int qblk = gridDim.x - 1 - blockIdx.x;   // longest blocks first
    const int h = blockIdx.y, b = blockIdx.z;
    const int tid = threadIdx.x, lane = tid & 63, wv = tid >> 6;
    const int l15 = lane & 15, g = lane >> 4;
    const int q0 = qblk * 64;
    const int qrow = q0 + wv * 16 + l15;

    auto stage = [&](int buf, int jb) {
#pragma unroll
        for (int inst = 0; inst < 4; ++inst) {
            int ci = inst * 256 + wv * 64 + lane;
            int rowk = ci >> 4, ck = ci & 15;
            gl_lds16(qkv + (size_t)(b * SEQ + jb * 64 + rowk) * FQKV + 1024 + h * 128
                         + ((ck ^ (rowk & 7)) << 3),
                     &Ks[buf][(inst * 256 + wv * 64) * 8]);
            int rowv = ci >> 3, cv = ci & 7;
            gl_lds16(vt + (size_t)((b * 8 + h) * 128 + rowv) * SEQ + jb * 64
                        + ((cv ^ (rowv & 7)) << 3),
                     &Vs[buf][(inst * 256 + wv * 64) * 8]);
        }
    };

    // Q fragments (B-operand): lane: q = l15, d = ks*32 + g*8 + j
    short8 qf[4];
    {
        const unsigned short* qb = qkv + (size_t)(b * SEQ + qrow) * FQKV + h * 128;
#pragma unroll
        for (int ks = 0; ks < 4; ++ks) qf[ks] = *(const short8*)(qb + ks * 32 + g * 8);
    }

    float m_r = -1e30f, l_r = 0.f;
    f32x4 o[8] = {};

    stage(0, 0);
    __syncthreads();
    int cur = 0;

    for (int jb = 0; jb <= qblk; ++jb) {
        if (jb < qblk) stage(cur ^ 1, jb + 1);

        // S^T = K * Q^T : 4 kv-fragments, accumulate over 4 d-slices
        f32x4 s[4] = {};
        __builtin_amdgcn_s_setprio(1);
#pragma unroll
        for (int ks = 0; ks < 4; ++ks) {
#pragma unroll
            for (int fi = 0; fi < 4; ++fi) {
                int rk = fi * 16 + l15;
                short8 kf = *(const short8*)&Ks[cur][rk * 128 + (((ks * 4 + g) ^ (rk & 7)) << 3)];
                s[fi] = __builtin_amdgcn_mfma_f32_16x16x32_bf16(kf, qf[ks], s[fi], 0, 0, 0);
            }
        }
        __builtin_amdgcn_s_setprio(0);

        if (jb == qblk) {   // diagonal tile: causal mask
#pragma unroll
            for (int fi = 0; fi < 4; ++fi)
#pragma unroll
                for (int v = 0; v < 4; ++v) {
                    int kv = q0 + fi * 16 + g * 4 + v;
                    if (kv > qrow) s[fi][v] = -1e30f;
                }
        }

        // online softmax (per q-row = lane&15, group reduce over lanes ^16,^32)
        float mx = -1e30f;
#pragma unroll
        for (int fi = 0; fi < 4; ++fi)
            mx = fmaxf(mx, fmaxf(fmaxf(s[fi][0], s[fi][1]), fmaxf(s[fi][2], s[fi][3])));
        mx = fmaxf(mx, __shfl_xor(mx, 16));
        mx = fmaxf(mx, __shfl_xor(mx, 32));
        float Mn = fmaxf(m_r, mx);
        float alpha = __expf(m_r - Mn);
        m_r = Mn;

        float ps = 0.f;
#pragma unroll
        for (int fi = 0; fi < 4; ++fi) {
#pragma unroll
            for (int p2 = 0; p2 < 2; ++p2) {
                unsigned short b0 = f2bf(__expf(s[fi][2 * p2] - Mn));
                unsigned short b1 = f2bf(__expf(s[fi][2 * p2 + 1] - Mn));
                ps += bf2f(b0) + bf2f(b1);   // denominator from rounded P: consistent with PV
                int kv = fi * 16 + g * 4 + 2 * p2;
                int addr = l15 * 64 + (((kv >> 3) ^ (l15 & 7)) << 3) + (kv & 7);
                *(unsigned int*)&Ps[wv][addr] = (unsigned int)b0 | ((unsigned int)b1 << 16);
            }
        }
        ps += __shfl_xor(ps, 16);
        ps += __shfl_xor(ps, 32);
        l_r = l_r * alpha + ps;

        // rescale O (alpha for row g*4+v lives in lane g*4+v)
        float av[4];
#pragma unroll
        for (int v = 0; v < 4; ++v) av[v] = __shfl(alpha, g * 4 + v);
#pragma unroll
        for (int fn = 0; fn < 8; ++fn) {
            o[fn][0] *= av[0]; o[fn][1] *= av[1]; o[fn][2] *= av[2]; o[fn][3] *= av[3];
        }

        // O += P * V
        __builtin_amdgcn_s_setprio(1);
#pragma unroll
        for (int ks = 0; ks < 2; ++ks) {
            short8 pa = *(const short8*)&Ps[wv][l15 * 64 + (((ks * 4 + g) ^ (l15 & 7)) << 3)];
#pragma unroll
            for (int fn = 0; fn < 8; ++fn) {
                int rv = fn * 16 + l15;
                short8 vf = *(const short8*)&Vs[cur][rv * 64 + (((ks * 4 + g) ^ (rv & 7)) << 3)];
                o[fn] = __builtin_amdgcn_mfma_f32_16x16x32_bf16(pa, vf, o[fn], 0, 0, 0);
            }
        }
        __builtin_amdgcn_s_setprio(0);

        __syncthreads();   // drains this iter's prefetch (issued before compute)
        cur ^= 1;
    }

    // epilogue: divide by l (row g*4+v's sum lives in lane g*4+v), store bf16
    float lv[4];
#pragma unroll
    for (int v = 0; v < 4; ++v) lv[v] = 1.0f / __shfl(l_r, g * 4 + v);
#pragma unroll
    for (int fn = 0; fn < 8; ++fn)
#pragma unroll
        for (int v = 0; v < 4; ++v) {
            int row = b * SEQ + q0 + wv * 16 + g * 4 + v;
            ao[(size_t)row * DIM + h * 128 + fn * 16 + l15] = f2bf(o[fn][v] * lv[v]);
        }
}

// ---------------------------------------------------------------------------
extern "C" void kernel_launch(void* const* d_in, const int* in_sizes, int n_in,
                              void* d_out, int out_size, void* d_ws, size_t ws_size,
                              hipStream_t stream) {
    const float* x     = (const float*)d_in[0];
    const float* gamma = (const float*)d_in[1];
    const float* w_qkv = (const float*)d_in[2];
    const float* w_out = (const float*)d_in[3];

    char* ws = (char*)d_ws;
    unsigned short* qkvb = (unsigned short*)ws;                   // 25165824 B  [4096][3072]
    unsigned short* vtb  = (unsigned short*)(ws + 25165824);      //  8388608 B  [16][128][2048]
    unsigned short* xnb  = (unsigned short*)(ws + 33554432);      //  8388608 B  [4096][1024]
    unsigned short* wqb  = (unsigned short*)(ws + 41943040);      //  6291456 B  [3072][1024]
    unsigned short* wob  = (unsigned short*)(ws + 48234496);      //  2097152 B  [1024][1024]
    unsigned short* aob  = (unsigned short*)(ws + 50331648);      //  8388608 B  [4096][1024]

    wconv<<<3072, 256, 0, stream>>>(w_qkv, wqb, 786432);
    wconv<<<1024, 256, 0, stream>>>(w_out, wob, 262144);
    l2norm_bf16<<<4096, 256, 0, stream>>>(x, gamma, xnb);
    gemm_bf16<1><<<dim3(24, 32), 256, 0, stream>>>(xnb, wqb, qkvb, NTOK, FQKV, DIM);
    transpose_v<<<dim3(32, 2, 16), 256, 0, stream>>>(qkvb, vtb);
    attn_mfma<<<dim3(32, 8, 2), 256, 0, stream>>>(qkvb, vtb, aob);
    gemm_bf16<0><<<dim3(8, 32), 256, 0, stream>>>(aob, wob, (float*)d_out, NTOK, DIM, DIM);
}

// Round 4
// 128.926 us; speedup vs baseline: 8.3905x; 1.1101x over previous
//
#include <hip/hip_runtime.h>

#define SEQ 2048
#define NTOK 4096
#define DIM 1024
#define FQKV 3072
#define SC_ATTN 0.08838834764831843f   // 128^-0.5
#define SC_Q (0.08838834764831843f * 1.4426950408889634f)  // fold log2e -> exp2 domain
#define SC_NORM 32.0f                  // sqrt(1024)

typedef short short8 __attribute__((ext_vector_type(8)));
typedef float f32x4 __attribute__((ext_vector_type(4)));
typedef unsigned short u16x4 __attribute__((ext_vector_type(4)));

__device__ __forceinline__ unsigned short f2bf(float f) {
    unsigned int u = __float_as_uint(f);
    u += 0x7fffu + ((u >> 16) & 1u);   // RNE
    return (unsigned short)(u >> 16);
}
__device__ __forceinline__ float bf2f(unsigned short b) {
    return __uint_as_float(((unsigned int)b) << 16);
}
__device__ __forceinline__ void gl_lds16(const void* g, void* l) {
    __builtin_amdgcn_global_load_lds((const __attribute__((address_space(1))) void*)g,
                                     (__attribute__((address_space(3))) void*)l, 16, 0, 0);
}

// ---------------------------------------------------------------------------
// L2 norm -> bf16
// ---------------------------------------------------------------------------
__global__ __launch_bounds__(256) void l2norm_bf16(const float* __restrict__ x,
                                                   const float* __restrict__ gamma,
                                                   unsigned short* __restrict__ xn) {
    int token = blockIdx.x;
    float4 v = ((const float4*)(x + (size_t)token * DIM))[threadIdx.x];
    float ss = v.x * v.x + v.y * v.y + v.z * v.z + v.w * v.w;
#pragma unroll
    for (int off = 32; off > 0; off >>= 1) ss += __shfl_down(ss, off);
    __shared__ float wsum[4];
    if ((threadIdx.x & 63) == 0) wsum[threadIdx.x >> 6] = ss;
    __syncthreads();
    float tot = wsum[0] + wsum[1] + wsum[2] + wsum[3];
    float sc = SC_NORM / fmaxf(sqrtf(tot), 1e-12f);
    float4 g = ((const float4*)gamma)[threadIdx.x];
    u16x4 o;
    o.x = f2bf(v.x * sc * g.x);
    o.y = f2bf(v.y * sc * g.y);
    o.z = f2bf(v.z * sc * g.z);
    o.w = f2bf(v.w * sc * g.w);
    ((u16x4*)(xn + (size_t)token * DIM))[threadIdx.x] = o;
}

// ---------------------------------------------------------------------------
// fp32 -> bf16 weight convert
// ---------------------------------------------------------------------------
__global__ __launch_bounds__(256) void wconv(const float* __restrict__ w,
                                             unsigned short* __restrict__ o, int n4) {
    int i = blockIdx.x * 256 + threadIdx.x;
    if (i >= n4) return;
    float4 v = ((const float4*)w)[i];
    u16x4 r;
    r.x = f2bf(v.x); r.y = f2bf(v.y); r.z = f2bf(v.z); r.w = f2bf(v.w);
    ((u16x4*)o)[i] = r;
}

// ---------------------------------------------------------------------------
// bf16 GEMM NT: C[M][N] = A[M][K] * B[N][K]^T. 128x128 tile, BK=64, 4 waves.
// Double-buffered LDS, prefetch before compute, one barrier per iter.
// C_MODE 0: f32 out. C_MODE 1: bf16 out, cols<1024 (Q) scaled by SC_Q.
// ---------------------------------------------------------------------------
template<int C_MODE>
__global__ __launch_bounds__(256) void gemm_bf16(const unsigned short* __restrict__ A,
                                                 const unsigned short* __restrict__ B,
                                                 void* __restrict__ Cv,
                                                 int M, int N, int K) {
    __shared__ unsigned short As[2][128 * 64];
    __shared__ unsigned short Bs[2][128 * 64];
    const int bn = blockIdx.x * 128, bm = blockIdx.y * 128;
    const int tid = threadIdx.x, lane = tid & 63, wv = tid >> 6;
    const int wr = wv >> 1, wc = wv & 1;
    const int l15 = lane & 15, g = lane >> 4;

    f32x4 acc[4][4] = {};

    auto stage = [&](int buf, int k0) {
#pragma unroll
        for (int inst = 0; inst < 4; ++inst) {
            int ci = inst * 256 + wv * 64 + lane;
            int row = ci >> 3, cc = ci & 7;
            int co = (cc ^ (row & 7)) << 3;
            gl_lds16(A + (size_t)(bm + row) * K + k0 + co, &As[buf][(inst * 256 + wv * 64) * 8]);
            gl_lds16(B + (size_t)(bn + row) * K + k0 + co, &Bs[buf][(inst * 256 + wv * 64) * 8]);
        }
    };

    stage(0, 0);
    __syncthreads();
    int cur = 0;
    for (int k0 = 0; k0 < K; k0 += 64) {
        if (k0 + 64 < K) stage(cur ^ 1, k0 + 64);
#pragma unroll
        for (int ks = 0; ks < 2; ++ks) {
            short8 af[4], bf[4];
#pragma unroll
            for (int f = 0; f < 4; ++f) {
                int ra = wr * 64 + f * 16 + l15;
                af[f] = *(const short8*)&As[cur][ra * 64 + (((ks * 4 + g) ^ (ra & 7)) << 3)];
                int rb = wc * 64 + f * 16 + l15;
                bf[f] = *(const short8*)&Bs[cur][rb * 64 + (((ks * 4 + g) ^ (rb & 7)) << 3)];
            }
#pragma unroll
            for (int i = 0; i < 4; ++i)
#pragma unroll
                for (int j = 0; j < 4; ++j)
                    acc[i][j] = __builtin_amdgcn_mfma_f32_16x16x32_bf16(af[i], bf[j], acc[i][j], 0, 0, 0);
        }
        __syncthreads();
        cur ^= 1;
    }

    if (C_MODE == 0) {
        float* C = (float*)Cv;
#pragma unroll
        for (int i = 0; i < 4; ++i)
#pragma unroll
            for (int j = 0; j < 4; ++j)
#pragma unroll
                for (int v = 0; v < 4; ++v) {
                    int row = bm + wr * 64 + i * 16 + g * 4 + v;
                    int col = bn + wc * 64 + j * 16 + l15;
                    C[(size_t)row * N + col] = acc[i][j][v];
                }
    } else {
        unsigned short* C = (unsigned short*)Cv;
        float s = (bn < 1024) ? SC_Q : 1.0f;
#pragma unroll
        for (int i = 0; i < 4; ++i)
#pragma unroll
            for (int j = 0; j < 4; ++j)
#pragma unroll
                for (int v = 0; v < 4; ++v) {
                    int row = bm + wr * 64 + i * 16 + g * 4 + v;
                    int col = bn + wc * 64 + j * 16 + l15;
                    C[(size_t)row * N + col] = f2bf(acc[i][j][v] * s);
                }
    }
}

// ---------------------------------------------------------------------------
// V transpose: qkv V-part [token][d] -> vt[(b*8+h)*128 + d][token]
// ---------------------------------------------------------------------------
__global__ __launch_bounds__(256) void transpose_v(const unsigned short* __restrict__ qkv,
                                                   unsigned short* __restrict__ vt) {
    __shared__ unsigned short T[64][72];
    const int t0 = blockIdx.x * 64, d0 = blockIdx.y * 64, bh = blockIdx.z;
    const int b = bh >> 3, h = bh & 7;
    const int tid = threadIdx.x;
#pragma unroll
    for (int p = 0; p < 2; ++p) {
        int r = p * 32 + (tid >> 3), c = tid & 7;
        *(short8*)&T[r][c * 8] =
            *(const short8*)(qkv + (size_t)(b * SEQ + t0 + r) * FQKV + 2048 + h * 128 + d0 + c * 8);
    }
    __syncthreads();
#pragma unroll
    for (int p = 0; p < 2; ++p) {
        int d = p * 32 + (tid >> 3), c = tid & 7;
        short8 v;
#pragma unroll
        for (int j = 0; j < 8; ++j) v[j] = (short)T[c * 8 + j][d];
        *(short8*)(vt + (size_t)(bh * 128 + d0 + d) * SEQ + t0 + c * 8) = v;
    }
}

// ---------------------------------------------------------------------------
// Flash attention, bf16 MFMA. 4 waves x 16 q-rows (QB=64), KB=64.
// Single-buffered LDS (40KB -> 4 blocks/CU). Split-KV: q-blocks >=16 are
// processed by TWO blocks (kv halves) writing fp32 partials (O,m,l); q-blocks
// <16 write final bf16 output directly. exp2 domain (Q pre-scaled by log2e).
// ---------------------------------------------------------------------------
__global__ __launch_bounds__(256) void attn_mfma(const unsigned short* __restrict__ qkv,
                                                 const unsigned short* __restrict__ vt,
                                                 unsigned short* __restrict__ ao,
                                                 float* __restrict__ po,
                                                 float* __restrict__ pml) {
    __shared__ unsigned short Ks[64 * 128];
    __shared__ unsigned short Vs[128 * 64];
    __shared__ unsigned short Ps[4][16 * 64];
    const int h = blockIdx.y, b = blockIdx.z;
    const int x = blockIdx.x;
    int qblk, jb0, jb1, split, slot;
    if (x < 32) {                       // split blocks (qblk 16..31), longest first
        qblk = 31 - (x >> 1);
        int s = x & 1;
        int T = qblk + 1, half = (T + 1) >> 1;
        jb0 = s ? half : 0;
        jb1 = s ? T : half;
        split = 1;
        slot = ((b * 8 + h) * 16 + (qblk - 16)) * 2 + s;
    } else {                            // unsplit (qblk 15..0)
        qblk = 47 - x;
        jb0 = 0; jb1 = qblk + 1;
        split = 0; slot = 0;
    }
    const int tid = threadIdx.x, lane = tid & 63, wv = tid >> 6;
    const int l15 = lane & 15, g = lane >> 4;
    const int q0 = qblk * 64;
    const int qrow = q0 + wv * 16 + l15;

    auto stage = [&](int jb) {
#pragma unroll
        for (int inst = 0; inst < 4; ++inst) {
            int ci = inst * 256 + wv * 64 + lane;
            int rowk = ci >> 4, ck = ci & 15;
            gl_lds16(qkv + (size_t)(b * SEQ + jb * 64 + rowk) * FQKV + 1024 + h * 128
                         + ((ck ^ (rowk & 7)) << 3),
                     &Ks[(inst * 256 + wv * 64) * 8]);
            int rowv = ci >> 3, cv = ci & 7;
            gl_lds16(vt + (size_t)((b * 8 + h) * 128 + rowv) * SEQ + jb * 64
                        + ((cv ^ (rowv & 7)) << 3),
                     &Vs[(inst * 256 + wv * 64) * 8]);
        }
    };

    // Q fragments (B-operand): lane: q = l15, d = ks*32 + g*8 + j
    short8 qf[4];
    {
        const unsigned short* qb = qkv + (size_t)(b * SEQ + qrow) * FQKV + h * 128;
#pragma unroll
        for (int ks = 0; ks < 4; ++ks) qf[ks] = *(const short8*)(qb + ks * 32 + g * 8);
    }

    float m_r = -1e30f, l_r = 0.f;
    f32x4 o[8] = {};

    for (int jb = jb0; jb < jb1; ++jb) {
        __syncthreads();   // prev iter's LDS reads complete before restage
        stage(jb);
        __syncthreads();   // staged K/V visible (barrier drains vmcnt)

        // S^T = K * Q^T : 4 kv-fragments, accumulate over 4 d-slices
        f32x4 s[4] = {};
        __builtin_amdgcn_s_setprio(1);
#pragma unroll
        for (int ks = 0; ks < 4; ++ks) {
#pragma unroll
            for (int fi = 0; fi < 4; ++fi) {
                int rk = fi * 16 + l15;
                short8 kf = *(const short8*)&Ks[rk * 128 + (((ks * 4 + g) ^ (rk & 7)) << 3)];
                s[fi] = __builtin_amdgcn_mfma_f32_16x16x32_bf16(kf, qf[ks], s[fi], 0, 0, 0);
            }
        }
        __builtin_amdgcn_s_setprio(0);

        if (jb == qblk) {   // diagonal tile: causal mask
#pragma unroll
            for (int fi = 0; fi < 4; ++fi)
#pragma unroll
                for (int v = 0; v < 4; ++v) {
                    int kv = q0 + fi * 16 + g * 4 + v;
                    if (kv > qrow) s[fi][v] = -1e30f;
                }
        }

        // online softmax in exp2 domain (per q-row = lane&15)
        float mx = -1e30f;
#pragma unroll
        for (int fi = 0; fi < 4; ++fi)
            mx = fmaxf(mx, fmaxf(fmaxf(s[fi][0], s[fi][1]), fmaxf(s[fi][2], s[fi][3])));
        mx = fmaxf(mx, __shfl_xor(mx, 16));
        mx = fmaxf(mx, __shfl_xor(mx, 32));
        float Mn = fmaxf(m_r, mx);
        float alpha = exp2f(m_r - Mn);
        m_r = Mn;

        float ps = 0.f;
#pragma unroll
        for (int fi = 0; fi < 4; ++fi) {
#pragma unroll
            for (int p2 = 0; p2 < 2; ++p2) {
                unsigned short b0 = f2bf(exp2f(s[fi][2 * p2] - Mn));
                unsigned short b1 = f2bf(exp2f(s[fi][2 * p2 + 1] - Mn));
                ps += bf2f(b0) + bf2f(b1);   // denominator from rounded P: consistent with PV
                int kv = fi * 16 + g * 4 + 2 * p2;
                int addr = l15 * 64 + (((kv >> 3) ^ (l15 & 7)) << 3) + (kv & 7);
                *(unsigned int*)&Ps[wv][addr] = (unsigned int)b0 | ((unsigned int)b1 << 16);
            }
        }
        ps += __shfl_xor(ps, 16);
        ps += __shfl_xor(ps, 32);
        l_r = l_r * alpha + ps;

        // rescale O (alpha for row g*4+v lives in lane g*4+v)
        float av[4];
#pragma unroll
        for (int v = 0; v < 4; ++v) av[v] = __shfl(alpha, g * 4 + v);
#pragma unroll
        for (int fn = 0; fn < 8; ++fn) {
            o[fn][0] *= av[0]; o[fn][1] *= av[1]; o[fn][2] *= av[2]; o[fn][3] *= av[3];
        }

        // O += P * V
        __builtin_amdgcn_s_setprio(1);
#pragma unroll
        for (int ks = 0; ks < 2; ++ks) {
            short8 pa = *(const short8*)&Ps[wv][l15 * 64 + (((ks * 4 + g) ^ (l15 & 7)) << 3)];
#pragma unroll
            for (int fn = 0; fn < 8; ++fn) {
                int rv = fn * 16 + l15;
                short8 vf = *(const short8*)&Vs[rv * 64 + (((ks * 4 + g) ^ (rv & 7)) << 3)];
                o[fn] = __builtin_amdgcn_mfma_f32_16x16x32_bf16(pa, vf, o[fn], 0, 0, 0);
            }
        }
        __builtin_amdgcn_s_setprio(0);
    }

    if (split) {
        // unnormalized fp32 partial O + (m,l)
        float* od = po + (size_t)slot * (64 * 128);
#pragma unroll
        for (int fn = 0; fn < 8; ++fn)
#pragma unroll
            for (int v = 0; v < 4; ++v)
                od[(wv * 16 + g * 4 + v) * 128 + fn * 16 + l15] = o[fn][v];
        if (g == 0) {
            pml[(size_t)slot * 128 + wv * 16 + l15] = m_r;
            pml[(size_t)slot * 128 + 64 + wv * 16 + l15] = l_r;
        }
    } else {
        float lv[4];
#pragma unroll
        for (int v = 0; v < 4; ++v) lv[v] = 1.0f / __shfl(l_r, g * 4 + v);
#pragma unroll
        for (int fn = 0; fn < 8; ++fn)
#pragma unroll
            for (int v = 0; v < 4; ++v) {
                int row = b * SEQ + q0 + wv * 16 + g * 4 + v;
                ao[(size_t)row * DIM + h * 128 + fn * 16 + l15] = f2bf(o[fn][v] * lv[v]);
            }
    }
}

// ---------------------------------------------------------------------------
// Combine the two KV-split partials -> normalized bf16 output
// one block per (b,h,qblk>=16); thread: row = tid>>2, d-chunk = (tid&3)*32
// ---------------------------------------------------------------------------
__global__ __launch_bounds__(256) void attn_combine(const float* __restrict__ po,
                                                    const float* __restrict__ pml,
                                                    unsigned short* __restrict__ ao) {
    int t = blockIdx.x;                    // (b,h,qi): 256 blocks
    int qi = t & 15, h = (t >> 4) & 7, b = t >> 7;
    int qblk = 16 + qi;
    int slot0 = ((b * 8 + h) * 16 + qi) * 2;
    int row = threadIdx.x >> 2;
    int dp = threadIdx.x & 3;
    float m0 = pml[(size_t)slot0 * 128 + row];
    float l0 = pml[(size_t)slot0 * 128 + 64 + row];
    float m1 = pml[(size_t)(slot0 + 1) * 128 + row];
    float l1 = pml[(size_t)(slot0 + 1) * 128 + 64 + row];
    float M = fmaxf(m0, m1);
    float w0 = exp2f(m0 - M), w1 = exp2f(m1 - M);
    float inv = 1.0f / (w0 * l0 + w1 * l1);
    w0 *= inv; w1 *= inv;
    const float4* O0 = (const float4*)(po + (size_t)slot0 * 8192 + row * 128 + dp * 32);
    const float4* O1 = (const float4*)(po + (size_t)(slot0 + 1) * 8192 + row * 128 + dp * 32);
    unsigned short* dst = ao + ((size_t)(b * SEQ + qblk * 64 + row)) * DIM + h * 128 + dp * 32;
#pragma unroll
    for (int j = 0; j < 8; ++j) {
        float4 a = O0[j], c = O1[j];
        u16x4 r;
        r.x = f2bf(w0 * a.x + w1 * c.x);
        r.y = f2bf(w0 * a.y + w1 * c.y);
        r.z = f2bf(w0 * a.z + w1 * c.z);
        r.w = f2bf(w0 * a.w + w1 * c.w);
        *(u16x4*)(dst + j * 4) = r;
    }
}

// ---------------------------------------------------------------------------
extern "C" void kernel_launch(void* const* d_in, const int* in_sizes, int n_in,
                              void* d_out, int out_size, void* d_ws, size_t ws_size,
                              hipStream_t stream) {
    const float* x     = (const float*)d_in[0];
    const float* gamma = (const float*)d_in[1];
    const float* w_qkv = (const float*)d_in[2];
    const float* w_out = (const float*)d_in[3];

    char* ws = (char*)d_ws;
    unsigned short* qkvb = (unsigned short*)ws;                   // 25165824 B  [4096][3072]
    unsigned short* vtb  = (unsigned short*)(ws + 25165824);      //  8388608 B  [16][128][2048]
    unsigned short* xnb  = (unsigned short*)(ws + 33554432);      //  8388608 B  [4096][1024]
    unsigned short* wqb  = (unsigned short*)(ws + 41943040);      //  6291456 B  [3072][1024]
    unsigned short* wob  = (unsigned short*)(ws + 48234496);      //  2097152 B  [1024][1024]
    unsigned short* aob  = (unsigned short*)(ws + 50331648);      //  8388608 B  [4096][1024]
    float*          pml  = (float*)(ws + 58720256);               //   262144 B  [512][128]
    float*          po   = (float*)d_out;   // d_out as scratch: 512 x 64 x 128 f32 = 16.8 MB

    wconv<<<3072, 256, 0, stream>>>(w_qkv, wqb, 786432);
    wconv<<<1024, 256, 0, stream>>>(w_out, wob, 262144);
    l2norm_bf16<<<4096, 256, 0, stream>>>(x, gamma, xnb);
    gemm_bf16<1><<<dim3(24, 32), 256, 0, stream>>>(xnb, wqb, qkvb, NTOK, FQKV, DIM);
    transpose_v<<<dim3(32, 2, 16), 256, 0, stream>>>(qkvb, vtb);
    attn_mfma<<<dim3(48, 8, 2), 256, 0, stream>>>(qkvb, vtb, aob, po, pml);
    attn_combine<<<256, 256, 0, stream>>>(po, pml, aob);
    gemm_bf16<0><<<dim3(8, 32), 256, 0, stream>>>(aob, wob, (float*)d_out, NTOK, DIM, DIM);
}